// Round 1
// baseline (1233.914 us; speedup 1.0000x reference)
//
#include <hip/hip_runtime.h>

typedef _Float16 half8_t __attribute__((ext_vector_type(8)));
typedef _Float16 half4_t __attribute__((ext_vector_type(4)));
typedef float    f32x4   __attribute__((ext_vector_type(4)));

#define BSZ 32
#define SEQ 256
#define DD  128
#define MAT 16384   // 128*128
#define NCH 16      // chunks per sequence
#define CL  16      // chunk length

// ---- swizzled LDS layout: 128 rows x 16 chunks of 16B (8 f16). chunk j of row m
// stored at physical chunk (j ^ (m&7)). Row stride 256B == 0 mod 32 banks, the
// xor spreads 16-lane quads across 8 bank-groups -> 2-way (free) on b128 reads.
__device__ __forceinline__ int sw_chunk(int m, int kb) { return (m << 4) + (kb ^ (m & 7)); }
__device__ __forceinline__ int sw_off(int m, int k)    { return (sw_chunk(m, k >> 3) << 3) + (k & 7); }

// 128x128x128 f16 matmul, fp32 acc. Ads: A normal layout [m][k] (swizzled).
// Bds: B transposed storage: row n holds B[:,n] (k contiguous, swizzled).
// Wave w -> 64x64 quadrant (qr,qc); 4x4 tiles of 16x16, mfma_f32_16x16x32_f16.
__device__ __forceinline__ void mm128(const _Float16* __restrict__ Ads,
                                      const _Float16* __restrict__ Bds,
                                      f32x4 acc[4][4],
                                      int qr, int qc, int quad, int l16) {
#pragma unroll
  for (int ks = 0; ks < 4; ++ks) {
    const int kb = ks * 4 + quad;   // lane supplies k = ks*32 + quad*8 + j
    half8_t a[4], b[4];
#pragma unroll
    for (int tr = 0; tr < 4; ++tr)
      a[tr] = *(const half8_t*)&Ads[sw_chunk(qr * 64 + tr * 16 + l16, kb) << 3];
#pragma unroll
    for (int tc = 0; tc < 4; ++tc)
      b[tc] = *(const half8_t*)&Bds[sw_chunk(qc * 64 + tc * 16 + l16, kb) << 3];
#pragma unroll
    for (int tr = 0; tr < 4; ++tr)
#pragma unroll
      for (int tc = 0; tc < 4; ++tc)
        acc[tr][tc] = __builtin_amdgcn_mfma_f32_16x16x32_f16(a[tr], b[tc], acc[tr][tc], 0, 0, 0);
  }
}

// stage plain row-major f16 matrix (global) -> swizzled LDS, coalesced uint4
__device__ __forceinline__ void stage_f16(const _Float16* __restrict__ src,
                                          _Float16* dst, int tid) {
#pragma unroll
  for (int it = 0; it < 8; ++it) {
    int idx = tid + it * 256;          // 2048 chunks of 16B
    int m = idx >> 4, kb = idx & 15;
    *(uint4*)&dst[sw_chunk(m, kb) << 3] = ((const uint4*)src)[idx];
  }
}

// acc (C-layout) -> Ads normal layout f16 (swizzled). 64 scalar u16 writes/lane.
__device__ __forceinline__ void acc_to_lds(_Float16* Ads, const f32x4 acc[4][4],
                                           int qr, int qc, int quad, int l16) {
#pragma unroll
  for (int tr = 0; tr < 4; ++tr)
#pragma unroll
    for (int tc = 0; tc < 4; ++tc) {
      int m0 = qr * 64 + tr * 16 + quad * 4;
      int n  = qc * 64 + tc * 16 + l16;
#pragma unroll
      for (int r = 0; r < 4; ++r) Ads[sw_off(m0 + r, n)] = (_Float16)acc[tr][tc][r];
    }
}

// P^T slot lives in bytes [32768,65536) of the fp32 output slot for (b,t).
__device__ __forceinline__ _Float16* pT_slot(float* out_all, int b, int t) {
  return (_Float16*)(out_all + (size_t)(b * SEQ + t) * MAT) + MAT;
}

// ---------------- phase 1: local prefix chains, emit P^T f16 ----------------
__global__ __launch_bounds__(256) void k_phase1(const float* __restrict__ in,
                                                float* __restrict__ out_all,
                                                _Float16* __restrict__ Sbuf) {
  __shared__ __align__(16) _Float16 Ads[MAT];
  __shared__ __align__(16) _Float16 Bds[MAT];
  const int tid = threadIdx.x;
  const int b = blockIdx.x >> 4, c = blockIdx.x & 15;
  const int t0 = c * CL;
  const int wave = tid >> 6, lane = tid & 63;
  const int qr = wave >> 1, qc = wave & 1, quad = lane >> 4, l16 = lane & 15;

  // stage A_{t0} fp32 -> f16, normal layout (A operand)
  {
    const f32x4* src = (const f32x4*)(in + (size_t)(b * SEQ + t0) * MAT);
#pragma unroll
    for (int it = 0; it < 16; ++it) {
      int g = tid + it * 256;
      f32x4 v = src[g];
      int e0 = g << 2, m = e0 >> 7, k0 = e0 & 127;
      half4_t hv;
      hv[0] = (_Float16)v[0]; hv[1] = (_Float16)v[1];
      hv[2] = (_Float16)v[2]; hv[3] = (_Float16)v[3];
      *(half4_t*)&Ads[(sw_chunk(m, k0 >> 3) << 3) + (k0 & 7)] = hv;
    }
  }
  __syncthreads();
  // P^T[t0] = A_{t0}^T : transposed read from LDS, coalesced 16B global stores
  {
    _Float16* dst = pT_slot(out_all, b, t0);
#pragma unroll
    for (int it = 0; it < 8; ++it) {
      int idx = tid + it * 256;
      int n = idx >> 4, m0 = (idx & 15) << 3;
      half8_t v;
#pragma unroll
      for (int j = 0; j < 8; ++j) v[j] = Ads[sw_off(m0 + j, n)];
      *(half8_t*)&dst[n * DD + m0] = v;
    }
  }

  f32x4 acc[4][4];
  for (int i = 1; i < CL; ++i) {
    // stage B = A_{t0+i}, transposed into Bds (row n = column n)
    {
      const f32x4* src = (const f32x4*)(in + (size_t)(b * SEQ + t0 + i) * MAT);
#pragma unroll
      for (int it = 0; it < 16; ++it) {
        int g = tid + it * 256;
        f32x4 v = src[g];
        int e0 = g << 2, k = e0 >> 7, n0 = e0 & 127;
        Bds[sw_off(n0 + 0, k)] = (_Float16)v[0];
        Bds[sw_off(n0 + 1, k)] = (_Float16)v[1];
        Bds[sw_off(n0 + 2, k)] = (_Float16)v[2];
        Bds[sw_off(n0 + 3, k)] = (_Float16)v[3];
      }
    }
    if (i > 1) acc_to_lds(Ads, acc, qr, qc, quad, l16);  // P_{i-1} -> A operand
    __syncthreads();
#pragma unroll
    for (int tr = 0; tr < 4; ++tr)
#pragma unroll
      for (int tc = 0; tc < 4; ++tc) { f32x4 z = {0.f, 0.f, 0.f, 0.f}; acc[tr][tc] = z; }
    mm128(Ads, Bds, acc, qr, qc, quad, l16);
    // write P^T[t0+i] f16 (4 contiguous f16 along m per lane -> 8B stores)
    {
      _Float16* dst = pT_slot(out_all, b, t0 + i);
#pragma unroll
      for (int tr = 0; tr < 4; ++tr)
#pragma unroll
        for (int tc = 0; tc < 4; ++tc) {
          int m0 = qr * 64 + tr * 16 + quad * 4;
          int n  = qc * 64 + tc * 16 + l16;
          half4_t hv;
          hv[0] = (_Float16)acc[tr][tc][0]; hv[1] = (_Float16)acc[tr][tc][1];
          hv[2] = (_Float16)acc[tr][tc][2]; hv[3] = (_Float16)acc[tr][tc][3];
          *(half4_t*)&dst[n * DD + m0] = hv;
        }
    }
    __syncthreads();   // all waves done reading Ads/Bds before next overwrite
  }

  if (c == 0) {        // S_0 = chunk-0 total, normal layout f16 in ws
    acc_to_lds(Ads, acc, qr, qc, quad, l16);
    __syncthreads();
    _Float16* dst = Sbuf + (size_t)b * NCH * MAT;
#pragma unroll
    for (int it = 0; it < 8; ++it) {
      int idx = tid + it * 256;
      int m = idx >> 4, kb = idx & 15;
      *(uint4*)&dst[idx << 3] = *(const uint4*)&Ads[sw_chunk(m, kb) << 3];
    }
  }
}

// ---------------- phase 2: scan chunk totals; write x = S_15 ----------------
__global__ __launch_bounds__(256) void k_phase2(const float* __restrict__ out_all,
                                                _Float16* __restrict__ Sbuf,
                                                float* __restrict__ out_x) {
  __shared__ __align__(16) _Float16 Ads[MAT];
  __shared__ __align__(16) _Float16 Bds[MAT];
  const int tid = threadIdx.x, b = blockIdx.x;
  const int wave = tid >> 6, lane = tid & 63;
  const int qr = wave >> 1, qc = wave & 1, quad = lane >> 4, l16 = lane & 15;

  stage_f16(Sbuf + (size_t)b * NCH * MAT, Ads, tid);   // S_0

  f32x4 acc[4][4];
  for (int cc = 1; cc < NCH; ++cc) {
    // B = T_cc^T = P^T[b, cc*CL + CL-1], already transposed f16
    stage_f16((const _Float16*)(out_all + (size_t)(b * SEQ + cc * CL + CL - 1) * MAT) + MAT,
              Bds, tid);
    __syncthreads();
#pragma unroll
    for (int tr = 0; tr < 4; ++tr)
#pragma unroll
      for (int tc = 0; tc < 4; ++tc) { f32x4 z = {0.f, 0.f, 0.f, 0.f}; acc[tr][tc] = z; }
    mm128(Ads, Bds, acc, qr, qc, quad, l16);
    __syncthreads();
    if (cc < NCH - 1) {
      acc_to_lds(Ads, acc, qr, qc, quad, l16);          // S_cc -> A operand
      __syncthreads();
      _Float16* dst = Sbuf + ((size_t)b * NCH + cc) * MAT;
#pragma unroll
      for (int it = 0; it < 8; ++it) {
        int idx = tid + it * 256;
        int m = idx >> 4, kb = idx & 15;
        *(uint4*)&dst[idx << 3] = *(const uint4*)&Ads[sw_chunk(m, kb) << 3];
      }
    } else {                                            // S_15 == full product -> x
      float* xo = out_x + (size_t)b * MAT;
#pragma unroll
      for (int tr = 0; tr < 4; ++tr)
#pragma unroll
        for (int tc = 0; tc < 4; ++tc) {
          int m0 = qr * 64 + tr * 16 + quad * 4;
          int n  = qc * 64 + tc * 16 + l16;
#pragma unroll
          for (int r = 0; r < 4; ++r) xo[(m0 + r) * DD + n] = acc[tr][tc][r];
        }
    }
  }
}

// ---------------- phase 3: out[t] = S_{c-1} * P_loc[t] (independent) --------
__global__ __launch_bounds__(256) void k_phase3(float* __restrict__ out_all,
                                                const _Float16* __restrict__ Sbuf) {
  __shared__ __align__(16) _Float16 Ads[MAT];
  __shared__ __align__(16) _Float16 Bds[MAT];
  const int tid = threadIdx.x;
  const int b = blockIdx.x >> 4, c = blockIdx.x & 15;
  const int wave = tid >> 6, lane = tid & 63;
  const int qr = wave >> 1, qc = wave & 1, quad = lane >> 4, l16 = lane & 15;

  if (c == 0) {        // A = I
    uint4 z; z.x = z.y = z.z = z.w = 0u;
#pragma unroll
    for (int it = 0; it < 8; ++it) *(uint4*)&Ads[(tid + it * 256) << 3] = z;
    __syncthreads();
    if (tid < DD) Ads[sw_off(tid, tid)] = (_Float16)1.0f;
  } else {
    stage_f16(Sbuf + ((size_t)b * NCH + (c - 1)) * MAT, Ads, tid);
  }

  f32x4 acc[4][4];
  for (int i = 0; i < CL; ++i) {
    const int t = c * CL + i;
    float* slot = out_all + (size_t)(b * SEQ + t) * MAT;
    stage_f16((const _Float16*)slot + MAT, Bds, tid);   // own P^T, in-place safe
    __syncthreads();                                     // staged before overwrite
#pragma unroll
    for (int tr = 0; tr < 4; ++tr)
#pragma unroll
      for (int tc = 0; tc < 4; ++tc) { f32x4 z = {0.f, 0.f, 0.f, 0.f}; acc[tr][tc] = z; }
    mm128(Ads, Bds, acc, qr, qc, quad, l16);
    // coalesced fp32 store (quad writes 64B segments)
#pragma unroll
    for (int tr = 0; tr < 4; ++tr)
#pragma unroll
      for (int tc = 0; tc < 4; ++tc) {
        int m0 = qr * 64 + tr * 16 + quad * 4;
        int n  = qc * 64 + tc * 16 + l16;
#pragma unroll
        for (int r = 0; r < 4; ++r) slot[(m0 + r) * DD + n] = acc[tr][tc][r];
      }
    __syncthreads();   // all waves done with Bds before restage
  }
}

extern "C" void kernel_launch(void* const* d_in, const int* in_sizes, int n_in,
                              void* d_out, int out_size, void* d_ws, size_t ws_size,
                              hipStream_t stream) {
  const float* in = (const float*)d_in[0];
  float* out_x   = (float*)d_out;                 // [32,128,128]
  float* out_all = out_x + (size_t)BSZ * MAT;     // [32,256,128,128]
  _Float16* Sbuf = (_Float16*)d_ws;               // 32*16 matrices f16 = 16 MiB

  k_phase1<<<dim3(BSZ * NCH), dim3(256), 0, stream>>>(in, out_all, Sbuf);
  k_phase2<<<dim3(BSZ), dim3(256), 0, stream>>>((const float*)out_all, Sbuf, out_x);
  k_phase3<<<dim3(BSZ * NCH), dim3(256), 0, stream>>>(out_all, Sbuf);
}